// Round 4
// baseline (570.478 us; speedup 1.0000x reference)
//
#include <hip/hip_runtime.h>
#include <cmath>

#define DIM    64
#define MCODE  512
#define ROWS   131072
#define QELEMS 8388608   // 32*4096*64
#define BM     128       // rows per block
#define BCODE  128       // codes per chunk
#define NCHUNK 4
#define TPB    256

// async global->LDS, 16B per lane; LDS dest = wave-uniform base + lane*16
__device__ __forceinline__ void async16(void* l, const void* g) {
    __builtin_amdgcn_global_load_lds(
        (const __attribute__((address_space(1))) unsigned int*)g,
        (__attribute__((address_space(3))) unsigned int*)l, 16, 0, 0);
}

#define COMP(v, c) ((c) == 0 ? (v).x : (c) == 1 ? (v).y : (c) == 2 ? (v).z : (v).w)

// ---------------- prep: c[m] = ||e_m||^2 (numpy pairwise order), zero accumulators
__global__ __launch_bounds__(512) void vq_prep(const float* __restrict__ E,
                                               float* __restrict__ cvec,
                                               unsigned int* __restrict__ counts,
                                               double* __restrict__ lsum) {
    const int m = threadIdx.x;            // 512 threads, 1 block
    counts[m] = 0u;
    if (m == 0) *lsum = 0.0;
    const float* e = E + (size_t)m * DIM;
    float r[8];
#pragma unroll
    for (int j = 0; j < 8; ++j) r[j] = e[j] * e[j];
#pragma unroll
    for (int i = 1; i < 8; ++i)
#pragma unroll
        for (int j = 0; j < 8; ++j) r[j] += e[8 * i + j] * e[8 * i + j];
    cvec[m] = ((r[0] + r[1]) + (r[2] + r[3])) + ((r[4] + r[5]) + (r[6] + r[7]));
}

// ---------------- main: x-register-resident distance GEMM + argmin + outputs
// LDS: ebuf[2][128*64] ping-pong; ebuf[1] initially holds the x block.
// Swizzle (both x and e): element [row][k], k-group g stored at col' = (g + row%16)%16.
__global__ __launch_bounds__(TPB, 2) void vq_main(const float* __restrict__ X,
                                                  const float* __restrict__ E,
                                                  const float* __restrict__ cvec,
                                                  float* __restrict__ out,
                                                  unsigned int* __restrict__ counts,
                                                  double* __restrict__ lsum) {
    __shared__ __align__(16) float ebuf[2][BCODE * DIM];   // 64 KB
    __shared__ float scall[MCODE];                         // 2 KB
    __shared__ int bidxs[BM];
    __shared__ unsigned int hist[MCODE];                   // 2 KB
    __shared__ double red[TPB / 64];

    const int tid = threadIdx.x;
    const int w  = tid >> 6;     // wave id
    const int rg = tid >> 4;     // 0..15 : thread rows  = rg + 16*xi
    const int cg = tid & 15;     // 0..15 : thread codes = cg + 16*ei

    for (int i = tid; i < MCODE; i += TPB) hist[i] = 0u;

    // ---- stage X block -> ebuf[1] (linear LDS dest, swizzled global source)
    const float* Xb = X + (size_t)blockIdx.x * BM * DIM;
#pragma unroll
    for (int i = 0; i < 8; ++i) {
        const int s = i * TPB + tid;                       // float4 slot
        const int row = s >> 4;
        const int gk = ((s & 15) - (row & 15)) & 15;       // source k-group
        async16(((float4*)ebuf[1]) + i * TPB + w * 64,
                (const float4*)Xb + row * 16 + gk);
    }
    // ---- stage E chunk 0 -> ebuf[0]
#pragma unroll
    for (int i = 0; i < 8; ++i) {
        const int s = i * TPB + tid;
        const int code = s >> 4;
        const int gk = ((s & 15) - (code & 15)) & 15;
        async16(((float4*)ebuf[0]) + i * TPB + w * 64,
                (const float4*)E + code * 16 + gk);
    }
    for (int i = tid; i < MCODE; i += TPB) scall[i] = cvec[i];
    __syncthreads();   // vmcnt(0): x + es0 staged

    // ---- x -> registers (one-time; 128 b128 broadcast reads)
    float4 xr[8][16];
#pragma unroll
    for (int xi = 0; xi < 8; ++xi) {
        const float* rp = ebuf[1] + (rg + 16 * xi) * DIM;  // row&15 == rg
#pragma unroll
        for (int g = 0; g < 16; ++g)
            xr[xi][g] = *(const float4*)(rp + ((((g + rg) & 15)) << 2));
    }

    // ---- ||x||^2 per row from regs, numpy pairwise 8-acc order
    float nx[8];
#pragma unroll
    for (int xi = 0; xi < 8; ++xi) {
        float r[8];
#pragma unroll
        for (int j = 0; j < 8; ++j) { const float t = COMP(xr[xi][j >> 2], j & 3); r[j] = t * t; }
#pragma unroll
        for (int i = 1; i < 8; ++i)
#pragma unroll
            for (int j = 0; j < 8; ++j) {
                const int k = 8 * i + j;
                const float t = COMP(xr[xi][k >> 2], k & 3);
                r[j] = fmaf(t, t, r[j]);
            }
        nx[xi] = ((r[0] + r[1]) + (r[2] + r[3])) + ((r[4] + r[5]) + (r[6] + r[7]));
    }

    float bd[8]; int bi[8];
#pragma unroll
    for (int xi = 0; xi < 8; ++xi) { bd[xi] = __builtin_inff(); bi[xi] = 0; }

    for (int ch = 0; ch < NCHUNK; ++ch) {
        // barrier: current chunk's es staged (vmcnt drained), and every thread is
        // done reading the buffer we are about to overwrite (x-reads at ch==0,
        // chunk ch-1's es otherwise)
        __syncthreads();
        if (ch < NCHUNK - 1) {   // stage next chunk into the dead buffer
            const float* Eb = E + (size_t)(ch + 1) * BCODE * DIM;
            float4* dst = (float4*)ebuf[(ch + 1) & 1];
#pragma unroll
            for (int i = 0; i < 8; ++i) {
                const int s = i * TPB + tid;
                const int code = s >> 4;
                const int gk = ((s & 15) - (code & 15)) & 15;
                async16(dst + i * TPB + w * 64, (const float4*)Eb + code * 16 + gk);
            }
        }
        const float* eb = ebuf[ch & 1] + cg * DIM;   // thread's code base (codes cg+16*ei)
        float scv[8];
#pragma unroll
        for (int ei = 0; ei < 8; ++ei) scv[ei] = scall[ch * BCODE + cg + 16 * ei];

        float acc[8][8];
#pragma unroll
        for (int xi = 0; xi < 8; ++xi)
#pragma unroll
            for (int ei = 0; ei < 8; ++ei) acc[xi][ei] = 0.f;

#pragma unroll 2
        for (int g = 0; g < 16; ++g) {
            const int eo = ((g + cg) & 15) << 2;     // swizzled col of this thread's codes
            float4 ev[8];
#pragma unroll
            for (int ei = 0; ei < 8; ++ei)
                ev[ei] = *(const float4*)(eb + ei * 16 * DIM + eo);   // imm offs ei*4096
#pragma unroll
            for (int xi = 0; xi < 8; ++xi) {
                const float4 xv = xr[xi][g];
#pragma unroll
                for (int ei = 0; ei < 8; ++ei) {     // k = 4g..4g+3 ascending (ref order)
                    acc[xi][ei] = fmaf(xv.x, ev[ei].x, acc[xi][ei]);
                    acc[xi][ei] = fmaf(xv.y, ev[ei].y, acc[xi][ei]);
                    acc[xi][ei] = fmaf(xv.z, ev[ei].z, acc[xi][ei]);
                    acc[xi][ei] = fmaf(xv.w, ev[ei].w, acc[xi][ei]);
                }
            }
        }

        // ---- combine + per-thread argmin (codes ascend within thread; strict <)
#pragma unroll
        for (int ei = 0; ei < 8; ++ei) {
            const int code = ch * BCODE + cg + 16 * ei;
#pragma unroll
            for (int xi = 0; xi < 8; ++xi) {
                const float d2 = fmaf(-2.f, acc[xi][ei], nx[xi]) + scv[ei];  // ref rounding
                if (d2 < bd[xi]) { bd[xi] = d2; bi[xi] = code; }
            }
        }
    }

    // ---- argmin reduce across the 16 cg lanes, ties -> smaller index
#pragma unroll
    for (int off = 1; off < 16; off <<= 1) {
#pragma unroll
        for (int xi = 0; xi < 8; ++xi) {
            const float od = __shfl_xor(bd[xi], off, 64);
            const int oi = __shfl_xor(bi[xi], off, 64);
            if (od < bd[xi] || (od == bd[xi] && oi < bi[xi])) { bd[xi] = od; bi[xi] = oi; }
        }
    }
    if (cg == 0) {
#pragma unroll
        for (int xi = 0; xi < 8; ++xi) {
            bidxs[rg + 16 * xi] = bi[xi];
            atomicAdd(&hist[bi[xi]], 1u);
        }
    }
    __syncthreads();

    // ---- epilogue: quantised_st + loss; x re-read from global (L2/L3-hot), coalesced
    float* outb = out + (size_t)blockIdx.x * BM * DIM;
    float ls = 0.f;
#pragma unroll
    for (int i = 0; i < 8; ++i) {
        const int gi = i * TPB + tid;       // float4 index in block
        const int row = gi >> 4;
        const int colL = gi & 15;
        const int bq = bidxs[row];
        const float4 qv = ((const float4*)E)[bq * 16 + colL];
        const float4 xv = ((const float4*)Xb)[gi];
        float4 o;
        { const float t = qv.x - xv.x; o.x = xv.x + t; const float dd = xv.x - qv.x; ls = fmaf(dd, dd, ls); }
        { const float t = qv.y - xv.y; o.y = xv.y + t; const float dd = xv.y - qv.y; ls = fmaf(dd, dd, ls); }
        { const float t = qv.z - xv.z; o.z = xv.z + t; const float dd = xv.z - qv.z; ls = fmaf(dd, dd, ls); }
        { const float t = qv.w - xv.w; o.w = xv.w + t; const float dd = xv.w - qv.w; ls = fmaf(dd, dd, ls); }
        ((float4*)outb)[gi] = o;
    }

    // ---- block loss reduction -> one double atomic
#pragma unroll
    for (int off = 32; off > 0; off >>= 1) ls += __shfl_down(ls, off);
    const int lane = tid & 63, wid = tid >> 6;
    if (lane == 0) red[wid] = (double)ls;
    __syncthreads();
    if (tid == 0) {
        double s = 0.0;
#pragma unroll
        for (int wv = 0; wv < TPB / 64; ++wv) s += red[wv];
        atomicAdd(lsum, s);
    }
    for (int i = tid; i < MCODE; i += TPB) {
        const unsigned int v = hist[i];
        if (v) atomicAdd(&counts[i], v);
    }
}

// ---------------- finalize: losses + perplexity
__global__ __launch_bounds__(512) void vq_fin(const unsigned int* __restrict__ counts,
                                              const double* __restrict__ lsum,
                                              float* __restrict__ out3) {
    __shared__ double sred[8];
    const int t = threadIdx.x;
    const double avg = (double)counts[t] / (double)ROWS;
    double term = avg * log(avg + 1e-10);
#pragma unroll
    for (int off = 32; off > 0; off >>= 1) term += __shfl_down(term, off);
    const int lane = t & 63, wid = t >> 6;
    if (lane == 0) sred[wid] = term;
    __syncthreads();
    if (t == 0) {
        double s = 0.0;
#pragma unroll
        for (int w = 0; w < 8; ++w) s += sred[w];
        const float perp = (float)exp(-s);
        const float rl = (float)(*lsum / (double)QELEMS);
        out3[0] = 0.25f * rl;   // commitment_loss
        out3[1] = rl;           // codebook_loss
        out3[2] = perp;         // perplexity
    }
}

extern "C" void kernel_launch(void* const* d_in, const int* in_sizes, int n_in,
                              void* d_out, int out_size, void* d_ws, size_t ws_size,
                              hipStream_t stream) {
    const float* X = (const float*)d_in[0];       // [32,4096,64] fp32
    const float* E = (const float*)d_in[1];       // [512,64] fp32
    float* out = (float*)d_out;                   // 8388608 + 3 floats

    double* lsum = (double*)d_ws;
    unsigned int* counts = (unsigned int*)((char*)d_ws + 8);
    float* cvec = (float*)((char*)d_ws + 8 + MCODE * sizeof(unsigned int));

    vq_prep<<<1, MCODE, 0, stream>>>(E, cvec, counts, lsum);
    vq_main<<<ROWS / BM, TPB, 0, stream>>>(X, E, cvec, out, counts, lsum);
    vq_fin<<<1, MCODE, 0, stream>>>(counts, lsum, out + QELEMS);
}

// Round 5
// 166.135 us; speedup vs baseline: 3.4338x; 3.4338x over previous
//
#include <hip/hip_runtime.h>
#include <cmath>

#define DIM    64
#define MCODE  512
#define ROWS   131072
#define QELEMS 8388608   // 32*4096*64
#define BM     128       // rows per block
#define TPB    256

typedef _Float16 f16x8 __attribute__((ext_vector_type(8)));
typedef float    f32x16 __attribute__((ext_vector_type(16)));

// async global->LDS, 16B per lane; LDS dest = wave-uniform base + lane*16
__device__ __forceinline__ void async16(void* l, const void* g) {
    __builtin_amdgcn_global_load_lds(
        (const __attribute__((address_space(1))) unsigned int*)g,
        (__attribute__((address_space(3))) unsigned int*)l, 16, 0, 0);
}

// ---------------- prep: cvec, semax, fp16-tiled codebook; zero accumulators
__global__ __launch_bounds__(512) void vq_prep(const float* __restrict__ E,
                                               float* __restrict__ cvec,
                                               float* __restrict__ semaxp,
                                               _Float16* __restrict__ Ebf,
                                               unsigned int* __restrict__ counts,
                                               double* __restrict__ lsum) {
    __shared__ float smax[512];
    const int m = threadIdx.x;            // 512 threads, 1 block
    counts[m] = 0u;
    if (m == 0) *lsum = 0.0;
    const float* e = E + (size_t)m * DIM;
    float r[8];
#pragma unroll
    for (int j = 0; j < 8; ++j) r[j] = e[j] * e[j];
#pragma unroll
    for (int i = 1; i < 8; ++i)
#pragma unroll
        for (int j = 0; j < 8; ++j) r[j] += e[8 * i + j] * e[8 * i + j];
    const float c = ((r[0] + r[1]) + (r[2] + r[3])) + ((r[4] + r[5]) + (r[6] + r[7]));
    cvec[m] = c;
    smax[m] = c;
    __syncthreads();
    for (int s = 256; s > 0; s >>= 1) {
        if (m < s) smax[m] = fmaxf(smax[m], smax[m + s]);
        __syncthreads();
    }
    if (m == 0) *semaxp = sqrtf(smax[0]) * 1.000001f;

    // fp16 codebook in MFMA-B tiled granule order:
    // code m: half=m>>8, t=(m>>5)&7, lrow=m&31; k-granule g (8 halfs) ->
    // ws granule index = half*2048 + (t*8+g)*32 + lrow
    const int half = m >> 8, t = (m >> 5) & 7, lrow = m & 31;
    f16x8* dst = (f16x8*)Ebf;
#pragma unroll
    for (int g = 0; g < 8; ++g) {
        f16x8 hv;
#pragma unroll
        for (int j = 0; j < 8; ++j) hv[j] = (_Float16)e[8 * g + j];
        dst[half * 2048 + (t * 8 + g) * 32 + lrow] = hv;
    }
}

// ---------------- main: f16-MFMA distance filter + exact fp32 rescue
__global__ __launch_bounds__(TPB, 2) void vq_main(const float* __restrict__ X,
                                                  const float* __restrict__ E,
                                                  const float* __restrict__ cvec,
                                                  const float* __restrict__ semaxp,
                                                  const _Float16* __restrict__ Ebf,
                                                  float* __restrict__ out,
                                                  unsigned int* __restrict__ counts,
                                                  double* __restrict__ lsum) {
    __shared__ __align__(16) float xs[BM * DIM];        // 32 KB, rotate-swizzled granules
    __shared__ __align__(16) _Float16 ebf[256 * DIM];   // 32 KB, one half of codes, tiled
    __shared__ float scall[MCODE];
    __shared__ float nxs[BM];
    __shared__ int bidxs[BM];
    __shared__ unsigned int hist[MCODE];
    __shared__ int rlist[BM];
    __shared__ int rcount;
    __shared__ double red[TPB / 64];

    const int tid = threadIdx.x;
    const int w = tid >> 6;
    const int l = tid & 63;
    const int lhalf = l >> 5;
    const int lrow = l & 31;

    for (int i = tid; i < MCODE; i += TPB) hist[i] = 0u;
    if (tid == 0) rcount = 0;

    // ---- stage X block (linear dest, rotate-swizzled source: granule g of row r
    //      stored at col' = (g + r%16)%16)
    const float* Xb = X + (size_t)blockIdx.x * BM * DIM;
#pragma unroll
    for (int i = 0; i < 8; ++i) {
        const int s = i * TPB + tid;
        const int row = s >> 4;
        const int gk = ((s & 15) - (row & 15)) & 15;
        async16(((float4*)xs) + i * TPB + w * 64, (const float4*)Xb + row * 16 + gk);
    }
    // ---- stage Ebf half 0 (identity copy, pre-tiled in ws)
#pragma unroll
    for (int i = 0; i < 8; ++i)
        async16(((f16x8*)ebf) + i * TPB + w * 64, (const f16x8*)Ebf + i * TPB + tid);
    for (int i = tid; i < MCODE; i += TPB) scall[i] = cvec[i];
    __syncthreads();

    // ---- ||x||^2 per row (numpy pairwise 8-acc, k = 4g+c) — exact, from LDS
    if (tid < BM) {
        const float4* xr = (const float4*)(xs + tid * DIM);
        float r[8];
        {
            float4 v = xr[(0 + (tid & 15)) & 15];
            r[0] = v.x * v.x; r[1] = v.y * v.y; r[2] = v.z * v.z; r[3] = v.w * v.w;
            v = xr[(1 + (tid & 15)) & 15];
            r[4] = v.x * v.x; r[5] = v.y * v.y; r[6] = v.z * v.z; r[7] = v.w * v.w;
        }
#pragma unroll
        for (int g = 2; g < 16; ++g) {
            const float4 v = xr[(g + (tid & 15)) & 15];
            const int b = (g & 1) * 4;
            r[b + 0] = fmaf(v.x, v.x, r[b + 0]);
            r[b + 1] = fmaf(v.y, v.y, r[b + 1]);
            r[b + 2] = fmaf(v.z, v.z, r[b + 2]);
            r[b + 3] = fmaf(v.w, v.w, r[b + 3]);
        }
        nxs[tid] = ((r[0] + r[1]) + (r[2] + r[3])) + ((r[4] + r[5]) + (r[6] + r[7]));
    }
    __syncthreads();

    // ---- per-lane A fragments (fp16) + per-slot nx
    // A: row = lane&31 (+32w), k = 16c + 8*lhalf + e
    f16x8 afr[4];
    const int xrow = w * 32 + lrow;
    const float* xp = xs + xrow * DIM;
#pragma unroll
    for (int c = 0; c < 4; ++c) {
        const int gA = 4 * c + 2 * lhalf;
        const float4 a0 = *(const float4*)(xp + ((((gA + 0) + (xrow & 15)) & 15) << 2));
        const float4 a1 = *(const float4*)(xp + ((((gA + 1) + (xrow & 15)) & 15) << 2));
        f16x8 v;
        v[0] = (_Float16)a0.x; v[1] = (_Float16)a0.y; v[2] = (_Float16)a0.z; v[3] = (_Float16)a0.w;
        v[4] = (_Float16)a1.x; v[5] = (_Float16)a1.y; v[6] = (_Float16)a1.z; v[7] = (_Float16)a1.w;
        afr[c] = v;
    }
    // C/D row map (verified): row = (reg&3) + 8*(reg>>2) + 4*(lane>>5)
    float nx[16];
#pragma unroll
    for (int s = 0; s < 16; ++s)
        nx[s] = nxs[w * 32 + (s & 3) + 8 * (s >> 2) + 4 * lhalf];

    float m1[16], m2[16]; int i1[16];
#pragma unroll
    for (int s = 0; s < 16; ++s) { m1[s] = __builtin_inff(); m2[s] = __builtin_inff(); i1[s] = 0; }

    for (int h = 0; h < 2; ++h) {
        if (h) {
            __syncthreads();   // all waves done reading ebf half 0
#pragma unroll
            for (int i = 0; i < 8; ++i)
                async16(((f16x8*)ebf) + i * TPB + w * 64,
                        (const f16x8*)Ebf + 2048 + i * TPB + tid);
            __syncthreads();
        }
#pragma unroll
        for (int t = 0; t < 8; ++t) {
            const int code = h * 256 + 32 * t + lrow;
            const float cm = scall[code];
            f16x8 bfr[4];
#pragma unroll
            for (int c = 0; c < 4; ++c)   // 64 consecutive granules per wave: conflict-free
                bfr[c] = ((const f16x8*)ebf)[(t * 8 + c * 2 + lhalf) * 32 + lrow];
            f32x16 acc;
#pragma unroll
            for (int s = 0; s < 16; ++s) acc[s] = 0.f;
#pragma unroll
            for (int c = 0; c < 4; ++c)
                acc = __builtin_amdgcn_mfma_f32_32x32x16_f16(afr[c], bfr[c], acc, 0, 0, 0);
#pragma unroll
            for (int s = 0; s < 16; ++s) {
                const float v = fmaf(-2.f, acc[s], nx[s]) + cm;
                const bool b = v < m1[s];
                m2[s] = b ? m1[s] : fminf(m2[s], v);
                i1[s] = b ? code : i1[s];
                m1[s] = b ? v : m1[s];
            }
        }
    }

    // ---- per-row reduce over the 32 lanes holding that row: global (m1,i1,m2)
    const float semax = *semaxp;
    const float KA = 0.00256f * semax + 6.3e-7f;   // Δ = sx*KA + nx*KB (rigorous + 1.3x)
    const float KB = 3.3e-7f;
#pragma unroll
    for (int s = 0; s < 16; ++s) {
        float d = m1[s]; int i = i1[s]; float sec = m2[s];
#pragma unroll
        for (int off = 1; off < 32; off <<= 1) {
            const float od = __shfl_xor(d, off, 64);
            const int oi = __shfl_xor(i, off, 64);
            const float os = __shfl_xor(sec, off, 64);
            sec = fminf(fminf(sec, os), fmaxf(d, od));
            const bool tk = od < d || (od == d && oi < i);
            d = tk ? od : d; i = tk ? oi : i;
        }
        const float delta = fmaf(sqrtf(nx[s]), KA, nx[s] * KB);
        if (lrow == 0) {
            const int row = w * 32 + (s & 3) + 8 * (s >> 2) + 4 * lhalf;
            if (sec > d + delta) {          // provably unique fp32 winner
                bidxs[row] = i;
                atomicAdd(&hist[i], 1u);
            } else {                        // ambiguous: exact fp32 rescan
                rlist[atomicAdd(&rcount, 1)] = row;
            }
        }
    }
    __syncthreads();

    // ---- rescue: exact fp32 rescan (identical arithmetic to the passing fp32 kernel)
    for (int q = w; q < rcount; q += TPB / 64) {
        const int row = rlist[q];
        const float nxr = nxs[row];
        const float4* xr4 = (const float4*)(xs + row * DIM);
        float4 xg[16];
#pragma unroll
        for (int g = 0; g < 16; ++g) xg[g] = xr4[(g + (row & 15)) & 15];
        float bmv = __builtin_inff(); int bix = 0;
#pragma unroll 1
        for (int t = 0; t < 8; ++t) {
            const int cde = l + 64 * t;
            const float4* ep = (const float4*)(E + (size_t)cde * DIM);
            float dacc = 0.f;
#pragma unroll
            for (int g = 0; g < 16; ++g) {   // sequential k: exact reference order
                const float4 ev = ep[g];
                dacc = fmaf(xg[g].x, ev.x, dacc);
                dacc = fmaf(xg[g].y, ev.y, dacc);
                dacc = fmaf(xg[g].z, ev.z, dacc);
                dacc = fmaf(xg[g].w, ev.w, dacc);
            }
            const float d2 = fmaf(-2.f, dacc, nxr) + scall[cde];
            if (d2 < bmv) { bmv = d2; bix = cde; }
        }
#pragma unroll
        for (int off = 1; off < 64; off <<= 1) {
            const float od = __shfl_xor(bmv, off, 64);
            const int oi = __shfl_xor(bix, off, 64);
            if (od < bmv || (od == bmv && oi < bix)) { bmv = od; bix = oi; }
        }
        if (l == 0) { bidxs[row] = bix; atomicAdd(&hist[bix], 1u); }
    }
    __syncthreads();

    // ---- epilogue: quantised_st + loss (x from LDS, E rows L2-hot)
    float* outb = out + (size_t)blockIdx.x * BM * DIM;
    float ls = 0.f;
#pragma unroll
    for (int i = 0; i < 8; ++i) {
        const int gi = i * TPB + tid;
        const int row = gi >> 4;
        const int colL = gi & 15;
        const int bq = bidxs[row];
        const float4 qv = ((const float4*)E)[bq * 16 + colL];
        const float4 xv = ((const float4*)(xs + row * DIM))[(colL + (row & 15)) & 15];
        float4 o;
        { const float t = qv.x - xv.x; o.x = xv.x + t; const float dd = xv.x - qv.x; ls = fmaf(dd, dd, ls); }
        { const float t = qv.y - xv.y; o.y = xv.y + t; const float dd = xv.y - qv.y; ls = fmaf(dd, dd, ls); }
        { const float t = qv.z - xv.z; o.z = xv.z + t; const float dd = xv.z - qv.z; ls = fmaf(dd, dd, ls); }
        { const float t = qv.w - xv.w; o.w = xv.w + t; const float dd = xv.w - qv.w; ls = fmaf(dd, dd, ls); }
        ((float4*)outb)[gi] = o;
    }

#pragma unroll
    for (int off = 32; off > 0; off >>= 1) ls += __shfl_down(ls, off);
    if (l == 0) red[w] = (double)ls;
    __syncthreads();
    if (tid == 0) {
        double s = 0.0;
#pragma unroll
        for (int wv = 0; wv < TPB / 64; ++wv) s += red[wv];
        atomicAdd(lsum, s);
    }
    for (int i = tid; i < MCODE; i += TPB) {
        const unsigned int v = hist[i];
        if (v) atomicAdd(&counts[i], v);
    }
}

// ---------------- finalize: losses + perplexity
__global__ __launch_bounds__(512) void vq_fin(const unsigned int* __restrict__ counts,
                                              const double* __restrict__ lsum,
                                              float* __restrict__ out3) {
    __shared__ double sred[8];
    const int t = threadIdx.x;
    const double avg = (double)counts[t] / (double)ROWS;
    double term = avg * log(avg + 1e-10);
#pragma unroll
    for (int off = 32; off > 0; off >>= 1) term += __shfl_down(term, off);
    const int lane = t & 63, wid = t >> 6;
    if (lane == 0) sred[wid] = term;
    __syncthreads();
    if (t == 0) {
        double s = 0.0;
#pragma unroll
        for (int w = 0; w < 8; ++w) s += sred[w];
        const float perp = (float)exp(-s);
        const float rl = (float)(*lsum / (double)QELEMS);
        out3[0] = 0.25f * rl;   // commitment_loss
        out3[1] = rl;           // codebook_loss
        out3[2] = perp;         // perplexity
    }
}

extern "C" void kernel_launch(void* const* d_in, const int* in_sizes, int n_in,
                              void* d_out, int out_size, void* d_ws, size_t ws_size,
                              hipStream_t stream) {
    const float* X = (const float*)d_in[0];       // [32,4096,64] fp32
    const float* E = (const float*)d_in[1];       // [512,64] fp32
    float* out = (float*)d_out;                   // 8388608 + 3 floats

    double* lsum = (double*)d_ws;                                  // 8 B
    unsigned int* counts = (unsigned int*)((char*)d_ws + 8);       // 2048 B
    float* cvec = (float*)((char*)d_ws + 8 + 2048);                // 2048 B
    float* semaxp = (float*)((char*)d_ws + 8 + 4096);              // 4 B (+pad)
    _Float16* Ebf = (_Float16*)((char*)d_ws + 4112);               // 65536 B, 16B-aligned

    vq_prep<<<1, MCODE, 0, stream>>>(E, cvec, semaxp, Ebf, counts, lsum);
    vq_main<<<ROWS / BM, TPB, 0, stream>>>(X, E, cvec, semaxp, Ebf, out, counts, lsum);
    vq_fin<<<1, MCODE, 0, stream>>>(counts, lsum, out + QELEMS);
}

// Round 6
// 155.838 us; speedup vs baseline: 3.6607x; 1.0661x over previous
//
#include <hip/hip_runtime.h>
#include <cmath>

#define DIM    64
#define MCODE  512
#define ROWS   131072
#define QELEMS 8388608   // 32*4096*64
#define BM     128       // rows per block
#define TPB    256

typedef _Float16 f16x8 __attribute__((ext_vector_type(8)));
typedef float    f32x16 __attribute__((ext_vector_type(16)));

#define COMP(v, c) ((c) == 0 ? (v).x : (c) == 1 ? (v).y : (c) == 2 ? (v).z : (v).w)

// async global->LDS, 16B per lane; LDS dest = wave-uniform base + lane*16
__device__ __forceinline__ void async16(void* l, const void* g) {
    __builtin_amdgcn_global_load_lds(
        (const __attribute__((address_space(1))) unsigned int*)g,
        (__attribute__((address_space(3))) unsigned int*)l, 16, 0, 0);
}

// ---------------- prep: cvec, semax, fp16-tiled codebook; zero accumulators
__global__ __launch_bounds__(512) void vq_prep(const float* __restrict__ E,
                                               float* __restrict__ cvec,
                                               float* __restrict__ semaxp,
                                               _Float16* __restrict__ Ebf,
                                               unsigned int* __restrict__ counts,
                                               double* __restrict__ lsum) {
    __shared__ float smax[512];
    const int m = threadIdx.x;            // 512 threads, 1 block
    counts[m] = 0u;
    if (m == 0) *lsum = 0.0;
    const float* e = E + (size_t)m * DIM;
    float r[8];
#pragma unroll
    for (int j = 0; j < 8; ++j) r[j] = e[j] * e[j];
#pragma unroll
    for (int i = 1; i < 8; ++i)
#pragma unroll
        for (int j = 0; j < 8; ++j) r[j] += e[8 * i + j] * e[8 * i + j];
    const float c = ((r[0] + r[1]) + (r[2] + r[3])) + ((r[4] + r[5]) + (r[6] + r[7]));
    cvec[m] = c;
    smax[m] = c;
    __syncthreads();
    for (int s = 256; s > 0; s >>= 1) {
        if (m < s) smax[m] = fmaxf(smax[m], smax[m + s]);
        __syncthreads();
    }
    if (m == 0) *semaxp = sqrtf(smax[0]) * 1.000001f;

    // fp16 codebook, MFMA-A tiled granule order:
    // code m: half=m>>8, t=(m>>5)&7, lrow=m&31; k-granule g (8 halfs) ->
    // granule index = half*2048 + (t*8+g)*32 + lrow
    const int half = m >> 8, t = (m >> 5) & 7, lrow = m & 31;
    f16x8* dst = (f16x8*)Ebf;
#pragma unroll
    for (int g = 0; g < 8; ++g) {
        f16x8 hv;
#pragma unroll
        for (int j = 0; j < 8; ++j) hv[j] = (_Float16)e[8 * g + j];
        dst[half * 2048 + (t * 8 + g) * 32 + lrow] = hv;
    }
}

// ---------------- main: f16-MFMA filter (codes=A-rows, x=B-cols) + exact rescue
__global__ __launch_bounds__(TPB, 4) void vq_main(const float* __restrict__ X,
                                                  const float* __restrict__ E,
                                                  const float* __restrict__ cvec,
                                                  const float* __restrict__ semaxp,
                                                  const _Float16* __restrict__ Ebf,
                                                  float* __restrict__ out,
                                                  unsigned int* __restrict__ counts,
                                                  double* __restrict__ lsum) {
    __shared__ __align__(16) _Float16 ebf[256 * DIM];   // 32 KB, one half of codes, tiled
    __shared__ float scall[MCODE];                      // 2 KB
    __shared__ int bidxs[BM];
    __shared__ unsigned int hist[MCODE];                // 2 KB
    __shared__ int rlist[BM];
    __shared__ int rcount;
    __shared__ double red[TPB / 64];

    const int tid = threadIdx.x;
    const int w = tid >> 6;
    const int l = tid & 63;
    const int lhalf = l >> 5;
    const int lrow = l & 31;

    for (int i = tid; i < MCODE; i += TPB) hist[i] = 0u;
    if (tid == 0) rcount = 0;

    // ---- stage Ebf half 0 (identity copy, pre-tiled) + scall
#pragma unroll
    for (int i = 0; i < 8; ++i)
        async16(((f16x8*)ebf) + i * TPB + w * 64, (const f16x8*)Ebf + i * TPB + tid);
    for (int i = tid; i < MCODE; i += TPB) scall[i] = cvec[i];

    // ---- x fragments straight from global: lane owns row w*32+lrow,
    //      k-granules 4c + 2*lhalf + {0,1}  (B-operand: col=lane&31, k=16c+8*lhalf+e)
    const float* Xb = X + (size_t)blockIdx.x * BM * DIM;
    const int xrow = w * 32 + lrow;
    const float4* xp = (const float4*)(Xb + xrow * DIM);
    f16x8 xfr[4];
    float nxa = 0.f;                       // approximate ||x||^2 (filter-delta only)
#pragma unroll
    for (int c = 0; c < 4; ++c) {
        const float4 a0 = xp[4 * c + 2 * lhalf + 0];
        const float4 a1 = xp[4 * c + 2 * lhalf + 1];
        nxa = fmaf(a0.x, a0.x, nxa); nxa = fmaf(a0.y, a0.y, nxa);
        nxa = fmaf(a0.z, a0.z, nxa); nxa = fmaf(a0.w, a0.w, nxa);
        nxa = fmaf(a1.x, a1.x, nxa); nxa = fmaf(a1.y, a1.y, nxa);
        nxa = fmaf(a1.z, a1.z, nxa); nxa = fmaf(a1.w, a1.w, nxa);
        f16x8 v;
        v[0] = (_Float16)a0.x; v[1] = (_Float16)a0.y; v[2] = (_Float16)a0.z; v[3] = (_Float16)a0.w;
        v[4] = (_Float16)a1.x; v[5] = (_Float16)a1.y; v[6] = (_Float16)a1.z; v[7] = (_Float16)a1.w;
        xfr[c] = v;
    }
    nxa += __shfl_xor(nxa, 32, 64);        // lane-pair holds complementary k halves

    // per-lane scalar trackers for its ONE row (v = cm - 2*dot; nx cancels in m2-m1)
    float m1 = __builtin_inff(), m2 = __builtin_inff();
    int i1 = 0;

    __syncthreads();   // ebf h0 + scall ready

    for (int h = 0; h < 2; ++h) {
        if (h) {
            __syncthreads();   // all waves done reading ebf half 0
#pragma unroll
            for (int i = 0; i < 8; ++i)
                async16(((f16x8*)ebf) + i * TPB + w * 64,
                        (const f16x8*)Ebf + 2048 + i * TPB + tid);
            __syncthreads();
        }
#pragma unroll
        for (int tt = 0; tt < 8; ++tt) {
            // A-frags: 32 codes of this block, tiled LDS (64 consecutive granules/wave)
            f16x8 bfr[4];
#pragma unroll
            for (int c = 0; c < 4; ++c)
                bfr[c] = ((const f16x8*)ebf)[(tt * 8 + c * 2 + lhalf) * 32 + lrow];
            // cm values for this lane's 16 code-slots: 4 broadcast float4 reads
            float4 cmv[4];
#pragma unroll
            for (int g = 0; g < 4; ++g)
                cmv[g] = *(const float4*)(scall + h * 256 + 32 * tt + 8 * g + 4 * lhalf);

            f32x16 acc;
#pragma unroll
            for (int s = 0; s < 16; ++s) acc[s] = 0.f;
#pragma unroll
            for (int c = 0; c < 4; ++c)
                acc = __builtin_amdgcn_mfma_f32_32x32x16_f16(bfr[c], xfr[c], acc, 0, 0, 0);

            const int cbase = h * 256 + 32 * tt + 4 * lhalf;
#pragma unroll
            for (int s = 0; s < 16; ++s) {   // codes ascend with s (within lane) ✓
                const float v = fmaf(-2.f, acc[s], COMP(cmv[s >> 2], s & 3));
                m2 = fminf(fmaxf(m1, v), m2);        // med3: new second-min
                const bool b = v < m1;               // strict < : first-min wins
                i1 = b ? cbase + (s & 3) + 8 * (s >> 2) : i1;
                m1 = b ? v : m1;
            }
        }
    }

    // ---- merge lane <-> lane+32 (disjoint code subsets of the same row)
    {
        const float od = __shfl_xor(m1, 32, 64);
        const int oi = __shfl_xor(i1, 32, 64);
        const float os = __shfl_xor(m2, 32, 64);
        m2 = fminf(fminf(m2, os), fmaxf(m1, od));
        const bool tk = od < m1 || (od == m1 && oi < i1);
        m1 = tk ? od : m1; i1 = tk ? oi : i1;
    }

    // ---- ambiguity test + commit (lanes 0..31 hold rows w*32+lane)
    {
        const float semax = *semaxp;
        const float KA = 0.00256f * semax + 6.3e-7f;
        const float KB = 4.5e-7f;     // covers fp32 combine-order rounding (~3 ulp of nx)
        const float delta = fmaf(sqrtf(nxa), KA, nxa * KB);
        if (lhalf == 0) {
            if (m2 - m1 > delta) {          // provably unique fp32 winner
                bidxs[xrow] = i1;
                atomicAdd(&hist[i1], 1u);
            } else {                        // ambiguous: exact fp32 rescan
                rlist[atomicAdd(&rcount, 1)] = xrow;
            }
        }
    }
    __syncthreads();

    // ---- rescue: exact fp32 rescan (identical arithmetic to the passing fp32 kernel)
    for (int q = w; q < rcount; q += TPB / 64) {
        const int row = rlist[q];
        const float4* xr4 = (const float4*)(Xb + row * DIM);
        float4 xg[16];
#pragma unroll
        for (int g = 0; g < 16; ++g) xg[g] = xr4[g];
        // exact ||x||^2, numpy pairwise 8-acc order
        float r[8];
#pragma unroll
        for (int j = 0; j < 8; ++j) { const float t = COMP(xg[j >> 2], j & 3); r[j] = t * t; }
#pragma unroll
        for (int i = 1; i < 8; ++i)
#pragma unroll
            for (int j = 0; j < 8; ++j) {
                const int k = 8 * i + j;
                const float t = COMP(xg[k >> 2], k & 3);
                r[j] = fmaf(t, t, r[j]);
            }
        const float nxr = ((r[0] + r[1]) + (r[2] + r[3])) + ((r[4] + r[5]) + (r[6] + r[7]));
        float bmv = __builtin_inff(); int bix = 0;
#pragma unroll 1
        for (int t = 0; t < 8; ++t) {
            const int cde = l + 64 * t;
            const float4* ep = (const float4*)(E + (size_t)cde * DIM);
            float dacc = 0.f;
#pragma unroll
            for (int g = 0; g < 16; ++g) {   // sequential k: exact reference order
                const float4 ev = ep[g];
                dacc = fmaf(xg[g].x, ev.x, dacc);
                dacc = fmaf(xg[g].y, ev.y, dacc);
                dacc = fmaf(xg[g].z, ev.z, dacc);
                dacc = fmaf(xg[g].w, ev.w, dacc);
            }
            const float d2 = fmaf(-2.f, dacc, nxr) + scall[cde];
            if (d2 < bmv) { bmv = d2; bix = cde; }
        }
#pragma unroll
        for (int off = 1; off < 64; off <<= 1) {
            const float od = __shfl_xor(bmv, off, 64);
            const int oi = __shfl_xor(bix, off, 64);
            if (od < bmv || (od == bmv && oi < bix)) { bmv = od; bix = oi; }
        }
        if (l == 0) { bidxs[row] = bix; atomicAdd(&hist[bix], 1u); }
    }
    __syncthreads();

    // ---- epilogue: quantised_st + loss (x re-read coalesced, L2/L3-hot; E L2-hot)
    float* outb = out + (size_t)blockIdx.x * BM * DIM;
    float ls = 0.f;
#pragma unroll
    for (int i = 0; i < 8; ++i) {
        const int gi = i * TPB + tid;
        const int row = gi >> 4;
        const int colL = gi & 15;
        const int bq = bidxs[row];
        const float4 qv = ((const float4*)E)[bq * 16 + colL];
        const float4 xv = ((const float4*)Xb)[gi];
        float4 o;
        { const float t = qv.x - xv.x; o.x = xv.x + t; const float dd = xv.x - qv.x; ls = fmaf(dd, dd, ls); }
        { const float t = qv.y - xv.y; o.y = xv.y + t; const float dd = xv.y - qv.y; ls = fmaf(dd, dd, ls); }
        { const float t = qv.z - xv.z; o.z = xv.z + t; const float dd = xv.z - qv.z; ls = fmaf(dd, dd, ls); }
        { const float t = qv.w - xv.w; o.w = xv.w + t; const float dd = xv.w - qv.w; ls = fmaf(dd, dd, ls); }
        ((float4*)outb)[gi] = o;
    }

#pragma unroll
    for (int off = 32; off > 0; off >>= 1) ls += __shfl_down(ls, off);
    if (l == 0) red[w] = (double)ls;
    __syncthreads();
    if (tid == 0) {
        double s = 0.0;
#pragma unroll
        for (int wv = 0; wv < TPB / 64; ++wv) s += red[wv];
        atomicAdd(lsum, s);
    }
    for (int i = tid; i < MCODE; i += TPB) {
        const unsigned int v = hist[i];
        if (v) atomicAdd(&counts[i], v);
    }
}

// ---------------- finalize: losses + perplexity
__global__ __launch_bounds__(512) void vq_fin(const unsigned int* __restrict__ counts,
                                              const double* __restrict__ lsum,
                                              float* __restrict__ out3) {
    __shared__ double sred[8];
    const int t = threadIdx.x;
    const double avg = (double)counts[t] / (double)ROWS;
    double term = avg * log(avg + 1e-10);
#pragma unroll
    for (int off = 32; off > 0; off >>= 1) term += __shfl_down(term, off);
    const int lane = t & 63, wid = t >> 6;
    if (lane == 0) sred[wid] = term;
    __syncthreads();
    if (t == 0) {
        double s = 0.0;
#pragma unroll
        for (int w = 0; w < 8; ++w) s += sred[w];
        const float perp = (float)exp(-s);
        const float rl = (float)(*lsum / (double)QELEMS);
        out3[0] = 0.25f * rl;   // commitment_loss
        out3[1] = rl;           // codebook_loss
        out3[2] = perp;         // perplexity
    }
}

extern "C" void kernel_launch(void* const* d_in, const int* in_sizes, int n_in,
                              void* d_out, int out_size, void* d_ws, size_t ws_size,
                              hipStream_t stream) {
    const float* X = (const float*)d_in[0];       // [32,4096,64] fp32
    const float* E = (const float*)d_in[1];       // [512,64] fp32
    float* out = (float*)d_out;                   // 8388608 + 3 floats

    double* lsum = (double*)d_ws;                                  // 8 B
    unsigned int* counts = (unsigned int*)((char*)d_ws + 8);       // 2048 B
    float* cvec = (float*)((char*)d_ws + 8 + 2048);                // 2048 B
    float* semaxp = (float*)((char*)d_ws + 8 + 4096);              // 4 B (+pad)
    _Float16* Ebf = (_Float16*)((char*)d_ws + 4112);               // 65536 B, 16B-aligned

    vq_prep<<<1, MCODE, 0, stream>>>(E, cvec, semaxp, Ebf, counts, lsum);
    vq_main<<<ROWS / BM, TPB, 0, stream>>>(X, E, cvec, semaxp, Ebf, out, counts, lsum);
    vq_fin<<<1, MCODE, 0, stream>>>(counts, lsum, out + QELEMS);
}